// Round 5
// baseline (530.687 us; speedup 1.0000x reference)
//
#include <hip/hip_runtime.h>

#define NUSR 60000
#define NITM 40000
#define NN   100000
#define EE   2000000
#define HD   128

#define BW   512                 // bucket width in nodes (CSR build)
#define NB   196                 // ceil(NN / BW)
#define EPB  8192                // edges per block in binning kernels
#define TILE 128                 // nodes per fused layer block

using bf16x8   = __attribute__((ext_vector_type(8))) short;
using f32x4    = __attribute__((ext_vector_type(4))) float;
using ushort4t = __attribute__((ext_vector_type(4))) unsigned short;
using ushort2t = __attribute__((ext_vector_type(2))) unsigned short;
using uint4t   = __attribute__((ext_vector_type(4))) unsigned int;

__device__ __forceinline__ unsigned short f2bf(float f) {
    unsigned int u = __float_as_uint(f);
    u += 0x7FFFu + ((u >> 16) & 1u);           // round-to-nearest-even
    return (unsigned short)(u >> 16);
}
__device__ __forceinline__ float bf2f(unsigned short s) {
    return __uint_as_float(((unsigned int)s) << 16);
}
// order-preserving bf16 <-> u16 key (unsigned compare order == float order)
__device__ __forceinline__ unsigned short keyof(unsigned short b) {
    return (b & 0x8000u) ? (unsigned short)~b : (unsigned short)(b | 0x8000u);
}
__device__ __forceinline__ unsigned short unkey16(unsigned short k) {
    return (k & 0x8000u) ? (unsigned short)(k ^ 0x8000u) : (unsigned short)~k;
}
// packed inverse key map on a u32 (2 keys)
__device__ __forceinline__ unsigned unkey32(unsigned k) {
    unsigned negsel = (~k & 0x80008000u) >> 15;
    return k ^ (0x80008000u | (negsel * 0x7FFFu));
}
__device__ __forceinline__ int swz(int row, int col) {
    return row * HD + (col ^ ((row & 7) << 3));
}
__device__ __forceinline__ ushort2t pkmax(ushort2t a, ushort2t b) {
    return __builtin_elementwise_max(a, b);
}

// ---------------- CSR build via 2-level bucket binning ----------------
__global__ __launch_bounds__(256) void bhist_k(const int* __restrict__ dst,
                                               int* __restrict__ bcnt) {
    __shared__ int h[NB];
    int t = threadIdx.x;
    if (t < NB) h[t] = 0;
    __syncthreads();
    int e0 = blockIdx.x * EPB;
    #pragma unroll 4
    for (int i = t; i < EPB; i += 256) {
        int e = e0 + i;
        if (e < EE) atomicAdd(&h[dst[e] >> 9], 1);
    }
    __syncthreads();
    if (t < NB && h[t]) atomicAdd(&bcnt[t], h[t]);
}

__global__ void bscan_k(const int* __restrict__ bcnt, int* __restrict__ bbase,
                        int* __restrict__ bcur, int* __restrict__ off) {
    __shared__ int s[256];
    int t = threadIdx.x;
    int v = (t < NB) ? bcnt[t] : 0;
    s[t] = v;
    __syncthreads();
    for (int d = 1; d < 256; d <<= 1) {
        int a = (t >= d) ? s[t - d] : 0;
        __syncthreads();
        s[t] += a;
        __syncthreads();
    }
    if (t < NB) { bbase[t] = s[t] - v; bcur[t] = s[t] - v; }
    if (t == NB - 1) { bbase[NB] = s[t]; off[NN] = EE; }
}

__global__ __launch_bounds__(256) void bscatter_k(const int* __restrict__ src,
                                                  const int* __restrict__ dst,
                                                  int* __restrict__ bcur,
                                                  unsigned int* __restrict__ bedge) {
    __shared__ int h[NB], base[NB];
    int t = threadIdx.x;
    if (t < NB) h[t] = 0;
    __syncthreads();
    int e0 = blockIdx.x * EPB;
    #pragma unroll 4
    for (int i = t; i < EPB; i += 256) {
        int e = e0 + i;
        if (e < EE) atomicAdd(&h[dst[e] >> 9], 1);
    }
    __syncthreads();
    if (t < NB) {
        int c = h[t];
        base[t] = c ? atomicAdd(&bcur[t], c) : 0;
        h[t] = 0;
    }
    __syncthreads();
    #pragma unroll 4
    for (int i = t; i < EPB; i += 256) {
        int e = e0 + i;
        if (e < EE) {
            int d = dst[e];
            int b = d >> 9;
            int p = base[b] + atomicAdd(&h[b], 1);
            bedge[p] = ((unsigned)(d - (b << 9)) << 17) | (unsigned)src[e];
        }
    }
}

__global__ __launch_bounds__(512) void bcsr_k(const unsigned int* __restrict__ bedge,
                                              const int* __restrict__ bbase,
                                              int* __restrict__ off,
                                              int* __restrict__ csr) {
    __shared__ int cnt[BW], cur[BW], sc[BW];
    int b = blockIdx.x, t = threadIdx.x;
    int n0 = b * BW;
    int nloc = min(BW, NN - n0);
    cnt[t] = 0;
    __syncthreads();
    int e0 = bbase[b], e1 = bbase[b + 1];
    for (int e = e0 + t; e < e1; e += 512)
        atomicAdd(&cnt[bedge[e] >> 17], 1);
    __syncthreads();
    int v = cnt[t];
    sc[t] = v;
    __syncthreads();
    for (int d = 1; d < BW; d <<= 1) {
        int a = (t >= d) ? sc[t - d] : 0;
        __syncthreads();
        sc[t] += a;
        __syncthreads();
    }
    int excl = sc[t] - v;
    if (t < nloc) { off[n0 + t] = e0 + excl; cur[t] = e0 + excl; }
    __syncthreads();
    for (int e = e0 + t; e < e1; e += 512) {
        unsigned ed = bedge[e];
        int p = atomicAdd(&cur[ed >> 17], 1);
        csr[p] = (int)(ed & 0x1FFFFu);
    }
}

// ---------------- fp32 -> bf16 weight convert (6 mats of 128x128) ------------
__global__ void cvt6_k(const float* __restrict__ a0, const float* __restrict__ a1,
                       const float* __restrict__ a2, const float* __restrict__ a3,
                       const float* __restrict__ a4, const float* __restrict__ a5,
                       unsigned short* __restrict__ out) {
    int i = blockIdx.x * 256 + threadIdx.x;
    const float* s;
    switch (i >> 14) {
        case 0: s = a0; break; case 1: s = a1; break; case 2: s = a2; break;
        case 3: s = a3; break; case 4: s = a4; break; default: s = a5; break;
    }
    out[i] = f2bf(s[i & 16383]);
}

// -------- proj: hkey[row] = key(bf16( x[row] @ w.T + b )), MFMA --------
__global__ __launch_bounds__(256) void proj_mfma_k(
    const float* __restrict__ x, const unsigned short* __restrict__ wb,
    const float* __restrict__ bias, unsigned short* __restrict__ hkey,
    int row_base, int nrows) {
    __shared__ unsigned short lw[HD * HD];
    int tid = threadIdx.x;
    #pragma unroll
    for (int it = 0; it < 16; ++it) {
        int flat = (it * 256 + tid) * 4;
        int row = flat >> 7, col = flat & 127;
        *(ushort4t*)&lw[swz(row, col)] = *(const ushort4t*)(wb + flat);
    }
    __syncthreads();
    int lane = tid & 63, w = tid >> 6;
    int l15 = lane & 15, l4 = lane >> 4;
    int m0 = blockIdx.x * 128 + w * 32;
    f32x4 acc[2][8] = {};
    #pragma unroll
    for (int kb = 0; kb < 4; ++kb) {
        bf16x8 a[2];
        #pragma unroll
        for (int rt = 0; rt < 2; ++rt) {
            int r = m0 + rt * 16 + l15;
            if (r >= nrows) r = nrows - 1;
            const float* ap = x + (size_t)(row_base + r) * HD + kb * 32 + l4 * 8;
            f32x4 v0 = *(const f32x4*)ap;
            f32x4 v1 = *(const f32x4*)(ap + 4);
            bf16x8 f;
            #pragma unroll
            for (int j = 0; j < 4; ++j) { f[j] = (short)f2bf(v0[j]); f[j + 4] = (short)f2bf(v1[j]); }
            a[rt] = f;
        }
        #pragma unroll
        for (int ct = 0; ct < 8; ++ct) {
            bf16x8 b = *(const bf16x8*)&lw[swz(ct * 16 + l15, kb * 32 + l4 * 8)];
            acc[0][ct] = __builtin_amdgcn_mfma_f32_16x16x32_bf16(a[0], b, acc[0][ct], 0, 0, 0);
            acc[1][ct] = __builtin_amdgcn_mfma_f32_16x16x32_bf16(a[1], b, acc[1][ct], 0, 0, 0);
        }
    }
    #pragma unroll
    for (int ct = 0; ct < 8; ++ct) {
        int col = ct * 16 + l15;
        float bv = bias[col];
        #pragma unroll
        for (int rt = 0; rt < 2; ++rt)
            #pragma unroll
            for (int j = 0; j < 4; ++j) {
                int r = m0 + rt * 16 + l4 * 4 + j;
                if (r < nrows)
                    hkey[(size_t)(row_base + r) * HD + col] = keyof(f2bf(acc[rt][ct][j] + bv));
            }
    }
}

// ---- fused layer: gather-max (keys) into LDS, then out = h + bl + agg@wl.T
// ---- + h@wr.T (relu?), h read from keys. 128-node tile, 8 waves.
__global__ __launch_bounds__(512) void layer_fused_k(
    const unsigned int* __restrict__ hkey,       // rows of 64 u32 (2 keys each)
    const int* __restrict__ off, const int* __restrict__ csr,
    const unsigned short* __restrict__ wlb, const float* __restrict__ bl,
    const unsigned short* __restrict__ wrb,
    unsigned short* __restrict__ hkey_out,       // layer0 path
    float* __restrict__ fout,                    // layer1 path
    int relu) {
    __shared__ unsigned short lagg[TILE * HD];   // 32 KB swizzled agg VALUES (bf16)
    int tid = threadIdx.x;
    int lane = tid & 63, w = tid >> 6;
    int base = blockIdx.x * TILE;

    // ---- gather phase: wave w aggregates its own 16 rows ----
    for (int i = 0; i < 16; ++i) {
        int lr = w * 16 + i;
        int node = base + lr;
        ushort2t m = {0, 0};                     // 0 < key(any finite bf16)
        int nonempty = 0;
        if (node < NN) {
            int s0 = off[node], s1 = off[node + 1];
            nonempty = (s1 > s0);
            int j = s0;
            for (; j + 7 < s1; j += 8) {
                int r0 = __builtin_amdgcn_readfirstlane(csr[j]);
                int r1 = __builtin_amdgcn_readfirstlane(csr[j + 1]);
                int r2 = __builtin_amdgcn_readfirstlane(csr[j + 2]);
                int r3 = __builtin_amdgcn_readfirstlane(csr[j + 3]);
                int r4 = __builtin_amdgcn_readfirstlane(csr[j + 4]);
                int r5 = __builtin_amdgcn_readfirstlane(csr[j + 5]);
                int r6 = __builtin_amdgcn_readfirstlane(csr[j + 6]);
                int r7 = __builtin_amdgcn_readfirstlane(csr[j + 7]);
                unsigned v0 = hkey[(size_t)r0 * 64 + lane];
                unsigned v1 = hkey[(size_t)r1 * 64 + lane];
                unsigned v2 = hkey[(size_t)r2 * 64 + lane];
                unsigned v3 = hkey[(size_t)r3 * 64 + lane];
                unsigned v4 = hkey[(size_t)r4 * 64 + lane];
                unsigned v5 = hkey[(size_t)r5 * 64 + lane];
                unsigned v6 = hkey[(size_t)r6 * 64 + lane];
                unsigned v7 = hkey[(size_t)r7 * 64 + lane];
                ushort2t p0 = pkmax(*(ushort2t*)&v0, *(ushort2t*)&v1);
                ushort2t p1 = pkmax(*(ushort2t*)&v2, *(ushort2t*)&v3);
                ushort2t p2 = pkmax(*(ushort2t*)&v4, *(ushort2t*)&v5);
                ushort2t p3 = pkmax(*(ushort2t*)&v6, *(ushort2t*)&v7);
                m = pkmax(m, pkmax(pkmax(p0, p1), pkmax(p2, p3)));
            }
            for (; j < s1; ++j) {
                int r = __builtin_amdgcn_readfirstlane(csr[j]);
                unsigned v = hkey[(size_t)r * 64 + lane];
                m = pkmax(m, *(ushort2t*)&v);
            }
        }
        unsigned outv = 0;                       // empty / OOB -> bf16 zeros
        if (nonempty) outv = unkey32(*(unsigned*)&m);
        *(unsigned*)&lagg[swz(lr, lane * 2)] = outv;
    }
    __syncthreads();

    // ---- MFMA phase: wave w computes rows w*16..+15 of the tile ----
    int l15 = lane & 15, l4 = lane >> 4;
    int m0r = w * 16;
    int arow = base + m0r + l15;
    if (arow >= NN) arow = NN - 1;
    f32x4 acc[8] = {};
    #pragma unroll
    for (int kb = 0; kb < 4; ++kb) {
        bf16x8 a1 = *(const bf16x8*)&lagg[swz(m0r + l15, kb * 32 + l4 * 8)];
        uint4t aw = *(const uint4t*)(hkey + (size_t)arow * 64 + kb * 16 + l4 * 4);
        bf16x8 a2;
        #pragma unroll
        for (int u = 0; u < 4; ++u) {
            unsigned d = unkey32(aw[u]);
            a2[2 * u]     = (short)(d & 0xFFFFu);
            a2[2 * u + 1] = (short)(d >> 16);
        }
        #pragma unroll
        for (int ct = 0; ct < 8; ++ct) {
            const unsigned short* wp = wlb + (size_t)(ct * 16 + l15) * HD + kb * 32 + l4 * 8;
            bf16x8 b1 = *(const bf16x8*)wp;
            bf16x8 b2 = *(const bf16x8*)(wp + (wrb - wlb));
            acc[ct] = __builtin_amdgcn_mfma_f32_16x16x32_bf16(a1, b1, acc[ct], 0, 0, 0);
            acc[ct] = __builtin_amdgcn_mfma_f32_16x16x32_bf16(a2, b2, acc[ct], 0, 0, 0);
        }
    }
    const unsigned short* hk16 = (const unsigned short*)hkey;
    #pragma unroll
    for (int ct = 0; ct < 8; ++ct) {
        int col = ct * 16 + l15;
        float bv = bl[col];
        #pragma unroll
        for (int j = 0; j < 4; ++j) {
            int r = base + m0r + l4 * 4 + j;
            if (r < NN) {
                float res = bf2f(unkey16(hk16[(size_t)r * HD + col]));
                float v = acc[ct][j] + bv + res;
                if (relu) v = fmaxf(v, 0.0f);
                if (fout) fout[(size_t)r * HD + col] = v;
                else      hkey_out[(size_t)r * HD + col] = keyof(f2bf(v));
            }
        }
    }
}

extern "C" void kernel_launch(void* const* d_in, const int* in_sizes, int n_in,
                              void* d_out, int out_size, void* d_ws, size_t ws_size,
                              hipStream_t stream) {
    const float* x      = (const float*)d_in[0];
    const int*   ei     = (const int*)d_in[1];
    const float* w_user = (const float*)d_in[3];
    const float* b_user = (const float*)d_in[4];
    const float* w_item = (const float*)d_in[5];
    const float* b_item = (const float*)d_in[6];
    const float* w_l0   = (const float*)d_in[7];
    const float* b_l0   = (const float*)d_in[8];
    const float* w_r0   = (const float*)d_in[9];
    const float* w_l1   = (const float*)d_in[10];
    const float* b_l1   = (const float*)d_in[11];
    const float* w_r1   = (const float*)d_in[12];

    const int* e_src = ei;
    const int* e_dst = ei + EE;

    char* ws = (char*)d_ws;
    size_t cur_off = 0;
    auto carve = [&](size_t bytes) {
        void* p = ws + cur_off;
        cur_off = (cur_off + bytes + 255) & ~(size_t)255;
        return p;
    };
    unsigned short* hkey0 = (unsigned short*)carve((size_t)NN * HD * 2);  // 25.6 MB
    unsigned short* hkey1 = (unsigned short*)carve((size_t)NN * HD * 2);
    unsigned short* wb    = (unsigned short*)carve((size_t)6 * HD * HD * 2);
    int*      off   = (int*)carve((size_t)(NN + 1) * 4);
    int*      csr   = (int*)carve((size_t)EE * 4);
    unsigned* bedge = (unsigned*)carve((size_t)EE * 4);
    int*      bcnt  = (int*)carve((NB + 1) * 4);
    int*      bbase = (int*)carve((NB + 1) * 4);
    int*      bcur  = (int*)carve((NB + 1) * 4);
    (void)ws_size;

    // ---- CSR build (bucket binning) ----
    hipMemsetAsync(bcnt, 0, (size_t)NB * 4, stream);
    int nbB = (EE + EPB - 1) / EPB;
    bhist_k<<<nbB, 256, 0, stream>>>(e_dst, bcnt);
    bscan_k<<<1, 256, 0, stream>>>(bcnt, bbase, bcur, off);
    bscatter_k<<<nbB, 256, 0, stream>>>(e_src, e_dst, bcur, bedge);
    bcsr_k<<<NB, 512, 0, stream>>>(bedge, bbase, off, csr);

    // ---- weights -> bf16 ----
    cvt6_k<<<(6 * HD * HD) / 256, 256, 0, stream>>>(w_user, w_item, w_l0, w_r0, w_l1, w_r1, wb);

    // ---- input projection (per node type), keys only ----
    proj_mfma_k<<<(NUSR + 127) / 128, 256, 0, stream>>>(x, wb,         b_user, hkey0, 0,    NUSR);
    proj_mfma_k<<<(NITM + 127) / 128, 256, 0, stream>>>(x, wb + 16384, b_item, hkey0, NUSR, NITM);

    int lblocks = (NN + TILE - 1) / TILE;        // 782
    // ---- layer 0 (fused agg+combine), relu, -> hkey1 ----
    layer_fused_k<<<lblocks, 512, 0, stream>>>(
        (const unsigned*)hkey0, off, csr, wb + 2 * 16384, b_l0, wb + 3 * 16384,
        hkey1, nullptr, 1);
    // ---- layer 1 (fused), -> d_out fp32 ----
    layer_fused_k<<<lblocks, 512, 0, stream>>>(
        (const unsigned*)hkey1, off, csr, wb + 4 * 16384, b_l1, wb + 5 * 16384,
        nullptr, (float*)d_out, 0);
}

// Round 6
// 388.078 us; speedup vs baseline: 1.3675x; 1.3675x over previous
//
#include <hip/hip_runtime.h>

#define NUSR 60000
#define NITM 40000
#define NN   100000
#define EE   2000000
#define HD   128

#define BW   512                 // bucket width in nodes (CSR build)
#define NB   196                 // ceil(NN / BW)
#define EPB  8192                // edges per block in binning kernels

using bf16x8   = __attribute__((ext_vector_type(8))) short;
using f32x4    = __attribute__((ext_vector_type(4))) float;
using ushort4t = __attribute__((ext_vector_type(4))) unsigned short;
using ushort8t = __attribute__((ext_vector_type(8))) unsigned short;
using uint4t   = __attribute__((ext_vector_type(4))) unsigned int;

__device__ __forceinline__ unsigned short f2bf(float f) {
    unsigned int u = __float_as_uint(f);
    u += 0x7FFFu + ((u >> 16) & 1u);           // round-to-nearest-even
    return (unsigned short)(u >> 16);
}
__device__ __forceinline__ float bf2f(unsigned short s) {
    return __uint_as_float(((unsigned int)s) << 16);
}
// order-preserving bf16 <-> u16 key (unsigned compare order == float order)
__device__ __forceinline__ unsigned short keyof(unsigned short b) {
    return (b & 0x8000u) ? (unsigned short)~b : (unsigned short)(b | 0x8000u);
}
__device__ __forceinline__ unsigned short unkey16(unsigned short k) {
    return (k & 0x8000u) ? (unsigned short)(k ^ 0x8000u) : (unsigned short)~k;
}
// packed inverse key map on a u32 (2 keys)
__device__ __forceinline__ unsigned unkey32(unsigned k) {
    unsigned negsel = (~k & 0x80008000u) >> 15;
    return k ^ (0x80008000u | (negsel * 0x7FFFu));
}
__device__ __forceinline__ int swz(int row, int col) {
    return row * HD + (col ^ ((row & 7) << 3));
}
__device__ __forceinline__ ushort8t pkmax8(ushort8t a, ushort8t b) {
    return __builtin_elementwise_max(a, b);
}

// ---------------- CSR build via 2-level bucket binning ----------------
__global__ __launch_bounds__(256) void bhist_k(const int* __restrict__ dst,
                                               int* __restrict__ bcnt) {
    __shared__ int h[NB];
    int t = threadIdx.x;
    if (t < NB) h[t] = 0;
    __syncthreads();
    int e0 = blockIdx.x * EPB;
    #pragma unroll 4
    for (int i = t; i < EPB; i += 256) {
        int e = e0 + i;
        if (e < EE) atomicAdd(&h[dst[e] >> 9], 1);
    }
    __syncthreads();
    if (t < NB && h[t]) atomicAdd(&bcnt[t], h[t]);
}

__global__ void bscan_k(const int* __restrict__ bcnt, int* __restrict__ bbase,
                        int* __restrict__ bcur, int* __restrict__ off) {
    __shared__ int s[256];
    int t = threadIdx.x;
    int v = (t < NB) ? bcnt[t] : 0;
    s[t] = v;
    __syncthreads();
    for (int d = 1; d < 256; d <<= 1) {
        int a = (t >= d) ? s[t - d] : 0;
        __syncthreads();
        s[t] += a;
        __syncthreads();
    }
    if (t < NB) { bbase[t] = s[t] - v; bcur[t] = s[t] - v; }
    if (t == NB - 1) { bbase[NB] = s[t]; off[NN] = EE; }
}

__global__ __launch_bounds__(256) void bscatter_k(const int* __restrict__ src,
                                                  const int* __restrict__ dst,
                                                  int* __restrict__ bcur,
                                                  unsigned int* __restrict__ bedge) {
    __shared__ int h[NB], base[NB];
    int t = threadIdx.x;
    if (t < NB) h[t] = 0;
    __syncthreads();
    int e0 = blockIdx.x * EPB;
    #pragma unroll 4
    for (int i = t; i < EPB; i += 256) {
        int e = e0 + i;
        if (e < EE) atomicAdd(&h[dst[e] >> 9], 1);
    }
    __syncthreads();
    if (t < NB) {
        int c = h[t];
        base[t] = c ? atomicAdd(&bcur[t], c) : 0;
        h[t] = 0;
    }
    __syncthreads();
    #pragma unroll 4
    for (int i = t; i < EPB; i += 256) {
        int e = e0 + i;
        if (e < EE) {
            int d = dst[e];
            int b = d >> 9;
            int p = base[b] + atomicAdd(&h[b], 1);
            bedge[p] = ((unsigned)(d - (b << 9)) << 17) | (unsigned)src[e];
        }
    }
}

__global__ __launch_bounds__(512) void bcsr_k(const unsigned int* __restrict__ bedge,
                                              const int* __restrict__ bbase,
                                              int* __restrict__ off,
                                              int* __restrict__ csr) {
    __shared__ int cnt[BW], cur[BW], sc[BW];
    int b = blockIdx.x, t = threadIdx.x;
    int n0 = b * BW;
    int nloc = min(BW, NN - n0);
    cnt[t] = 0;
    __syncthreads();
    int e0 = bbase[b], e1 = bbase[b + 1];
    for (int e = e0 + t; e < e1; e += 512)
        atomicAdd(&cnt[bedge[e] >> 17], 1);
    __syncthreads();
    int v = cnt[t];
    sc[t] = v;
    __syncthreads();
    for (int d = 1; d < BW; d <<= 1) {
        int a = (t >= d) ? sc[t - d] : 0;
        __syncthreads();
        sc[t] += a;
        __syncthreads();
    }
    int excl = sc[t] - v;
    if (t < nloc) { off[n0 + t] = e0 + excl; cur[t] = e0 + excl; }
    __syncthreads();
    for (int e = e0 + t; e < e1; e += 512) {
        unsigned ed = bedge[e];
        int p = atomicAdd(&cur[ed >> 17], 1);
        csr[p] = (int)(ed & 0x1FFFFu);
    }
}

// ---------------- fp32 -> bf16 weight convert (6 mats of 128x128) ------------
__global__ void cvt6_k(const float* __restrict__ a0, const float* __restrict__ a1,
                       const float* __restrict__ a2, const float* __restrict__ a3,
                       const float* __restrict__ a4, const float* __restrict__ a5,
                       unsigned short* __restrict__ out) {
    int i = blockIdx.x * 256 + threadIdx.x;
    const float* s;
    switch (i >> 14) {
        case 0: s = a0; break; case 1: s = a1; break; case 2: s = a2; break;
        case 3: s = a3; break; case 4: s = a4; break; default: s = a5; break;
    }
    out[i] = f2bf(s[i & 16383]);
}

// -------- proj: hkey[row] = key(bf16( x[row] @ w.T + b )), MFMA --------
__global__ __launch_bounds__(256) void proj_mfma_k(
    const float* __restrict__ x, const unsigned short* __restrict__ wb,
    const float* __restrict__ bias, unsigned short* __restrict__ hkey,
    int row_base, int nrows) {
    __shared__ unsigned short lw[HD * HD];
    int tid = threadIdx.x;
    #pragma unroll
    for (int it = 0; it < 16; ++it) {
        int flat = (it * 256 + tid) * 4;
        int row = flat >> 7, col = flat & 127;
        *(ushort4t*)&lw[swz(row, col)] = *(const ushort4t*)(wb + flat);
    }
    __syncthreads();
    int lane = tid & 63, w = tid >> 6;
    int l15 = lane & 15, l4 = lane >> 4;
    int m0 = blockIdx.x * 128 + w * 32;
    f32x4 acc[2][8] = {};
    #pragma unroll
    for (int kb = 0; kb < 4; ++kb) {
        bf16x8 a[2];
        #pragma unroll
        for (int rt = 0; rt < 2; ++rt) {
            int r = m0 + rt * 16 + l15;
            if (r >= nrows) r = nrows - 1;
            const float* ap = x + (size_t)(row_base + r) * HD + kb * 32 + l4 * 8;
            f32x4 v0 = *(const f32x4*)ap;
            f32x4 v1 = *(const f32x4*)(ap + 4);
            bf16x8 f;
            #pragma unroll
            for (int j = 0; j < 4; ++j) { f[j] = (short)f2bf(v0[j]); f[j + 4] = (short)f2bf(v1[j]); }
            a[rt] = f;
        }
        #pragma unroll
        for (int ct = 0; ct < 8; ++ct) {
            bf16x8 b = *(const bf16x8*)&lw[swz(ct * 16 + l15, kb * 32 + l4 * 8)];
            acc[0][ct] = __builtin_amdgcn_mfma_f32_16x16x32_bf16(a[0], b, acc[0][ct], 0, 0, 0);
            acc[1][ct] = __builtin_amdgcn_mfma_f32_16x16x32_bf16(a[1], b, acc[1][ct], 0, 0, 0);
        }
    }
    #pragma unroll
    for (int ct = 0; ct < 8; ++ct) {
        int col = ct * 16 + l15;
        float bv = bias[col];
        #pragma unroll
        for (int rt = 0; rt < 2; ++rt)
            #pragma unroll
            for (int j = 0; j < 4; ++j) {
                int r = m0 + rt * 16 + l4 * 4 + j;
                if (r < nrows)
                    hkey[(size_t)(row_base + r) * HD + col] = keyof(f2bf(acc[rt][ct][j] + bv));
            }
    }
}

// -------- segment max on u16 keys; 4 edge-rows per wave-load (uint4/lane) ----
__global__ __launch_bounds__(256) void agg_key_k(
    const uint4t* __restrict__ hkey4,            // row = 16 x uint4 (256 B)
    const int* __restrict__ off, const int* __restrict__ csr,
    uint4t* __restrict__ agg4) {                 // values bf16, row = 16 x uint4
    int node = (blockIdx.x * 256 + threadIdx.x) >> 6;
    int lane = threadIdx.x & 63;
    if (node >= NN) return;
    int s0 = off[node], s1 = off[node + 1];
    int q = lane >> 4, l16 = lane & 15;          // quarter handles every 4th edge
    ushort8t m = {0, 0, 0, 0, 0, 0, 0, 0};       // 0 < key(any finite bf16)
    int j = s0;
    for (; j + 15 < s1; j += 16) {               // 16 edges = 4 wave-loads
        #pragma unroll
        for (int u = 0; u < 4; ++u) {
            int r = csr[j + u * 4 + q];
            uint4t v = hkey4[(size_t)r * 16 + l16];
            m = pkmax8(m, *(ushort8t*)&v);
        }
    }
    for (; j < s1; j += 4) {                     // tail: duplicate-pad (max idempotent)
        int jj = j + q;
        if (jj >= s1) jj = s1 - 1;
        int r = csr[jj];
        uint4t v = hkey4[(size_t)r * 16 + l16];
        m = pkmax8(m, *(ushort8t*)&v);
    }
    // merge the 4 quarters: xor-16 then xor-32 lane swaps
    uint4t mu = *(uint4t*)&m;
    uint4t o;
    #pragma unroll
    for (int c = 0; c < 4; ++c) o[c] = (unsigned)__shfl_xor((int)mu[c], 16, 64);
    mu = *(uint4t*)&( *(ushort8t*)&mu = pkmax8(*(ushort8t*)&mu, *(ushort8t*)&o) );
    #pragma unroll
    for (int c = 0; c < 4; ++c) o[c] = (unsigned)__shfl_xor((int)mu[c], 32, 64);
    *(ushort8t*)&mu = pkmax8(*(ushort8t*)&mu, *(ushort8t*)&o);
    if (q == 0) {
        uint4t outv = {0, 0, 0, 0};
        if (s1 > s0) {
            #pragma unroll
            for (int c = 0; c < 4; ++c) outv[c] = unkey32(mu[c]);
        }
        agg4[(size_t)node * 16 + l16] = outv;
    }
}

// ----- combine: out = h + bl + agg@wl.T + h@wr.T  (relu?), h from keys -------
__global__ __launch_bounds__(256) void combine_mfma_k(
    const unsigned short* __restrict__ hkey, const unsigned short* __restrict__ aggb,
    const unsigned short* __restrict__ wlb, const float* __restrict__ bl,
    const unsigned short* __restrict__ wrb,
    unsigned short* __restrict__ hkey_out, float* __restrict__ fout, int relu) {
    int tid = threadIdx.x;
    int lane = tid & 63, w = tid >> 6;
    int l15 = lane & 15, l4 = lane >> 4;
    int m0 = blockIdx.x * 128 + w * 32;
    const uint4t* hk4 = (const uint4t*)hkey;
    f32x4 acc[2][8] = {};
    #pragma unroll
    for (int kb = 0; kb < 4; ++kb) {
        bf16x8 a1[2], a2[2];
        #pragma unroll
        for (int rt = 0; rt < 2; ++rt) {
            int r = m0 + rt * 16 + l15;
            if (r >= NN) r = NN - 1;
            size_t o = (size_t)r * HD + kb * 32 + l4 * 8;
            a1[rt] = *(const bf16x8*)(aggb + o);
            uint4t aw = hk4[(size_t)r * 16 + kb * 4 + l4];
            bf16x8 f;
            #pragma unroll
            for (int u = 0; u < 4; ++u) {
                unsigned d = unkey32(aw[u]);
                f[2 * u]     = (short)(d & 0xFFFFu);
                f[2 * u + 1] = (short)(d >> 16);
            }
            a2[rt] = f;
        }
        #pragma unroll
        for (int ct = 0; ct < 8; ++ct) {
            size_t wp = (size_t)(ct * 16 + l15) * HD + kb * 32 + l4 * 8;
            bf16x8 b1 = *(const bf16x8*)(wlb + wp);
            bf16x8 b2 = *(const bf16x8*)(wrb + wp);
            acc[0][ct] = __builtin_amdgcn_mfma_f32_16x16x32_bf16(a1[0], b1, acc[0][ct], 0, 0, 0);
            acc[0][ct] = __builtin_amdgcn_mfma_f32_16x16x32_bf16(a2[0], b2, acc[0][ct], 0, 0, 0);
            acc[1][ct] = __builtin_amdgcn_mfma_f32_16x16x32_bf16(a1[1], b1, acc[1][ct], 0, 0, 0);
            acc[1][ct] = __builtin_amdgcn_mfma_f32_16x16x32_bf16(a2[1], b2, acc[1][ct], 0, 0, 0);
        }
    }
    #pragma unroll
    for (int ct = 0; ct < 8; ++ct) {
        int col = ct * 16 + l15;
        float bv = bl[col];
        #pragma unroll
        for (int rt = 0; rt < 2; ++rt)
            #pragma unroll
            for (int j = 0; j < 4; ++j) {
                int r = m0 + rt * 16 + l4 * 4 + j;
                if (r < NN) {
                    float res = bf2f(unkey16(hkey[(size_t)r * HD + col]));
                    float v = acc[rt][ct][j] + bv + res;
                    if (relu) v = fmaxf(v, 0.0f);
                    if (fout) fout[(size_t)r * HD + col] = v;
                    else      hkey_out[(size_t)r * HD + col] = keyof(f2bf(v));
                }
            }
    }
}

extern "C" void kernel_launch(void* const* d_in, const int* in_sizes, int n_in,
                              void* d_out, int out_size, void* d_ws, size_t ws_size,
                              hipStream_t stream) {
    const float* x      = (const float*)d_in[0];
    const int*   ei     = (const int*)d_in[1];
    const float* w_user = (const float*)d_in[3];
    const float* b_user = (const float*)d_in[4];
    const float* w_item = (const float*)d_in[5];
    const float* b_item = (const float*)d_in[6];
    const float* w_l0   = (const float*)d_in[7];
    const float* b_l0   = (const float*)d_in[8];
    const float* w_r0   = (const float*)d_in[9];
    const float* w_l1   = (const float*)d_in[10];
    const float* b_l1   = (const float*)d_in[11];
    const float* w_r1   = (const float*)d_in[12];

    const int* e_src = ei;
    const int* e_dst = ei + EE;

    char* ws = (char*)d_ws;
    size_t cur_off = 0;
    auto carve = [&](size_t bytes) {
        void* p = ws + cur_off;
        cur_off = (cur_off + bytes + 255) & ~(size_t)255;
        return p;
    };
    unsigned short* hkey0 = (unsigned short*)carve((size_t)NN * HD * 2);  // 25.6 MB
    unsigned short* hkey1 = (unsigned short*)carve((size_t)NN * HD * 2);
    unsigned short* aggb  = (unsigned short*)carve((size_t)NN * HD * 2);
    unsigned short* wb    = (unsigned short*)carve((size_t)6 * HD * HD * 2);
    int*      off   = (int*)carve((size_t)(NN + 1) * 4);
    int*      csr   = (int*)carve((size_t)EE * 4);
    unsigned* bedge = (unsigned*)carve((size_t)EE * 4);
    int*      bcnt  = (int*)carve((NB + 1) * 4);
    int*      bbase = (int*)carve((NB + 1) * 4);
    int*      bcur  = (int*)carve((NB + 1) * 4);
    (void)ws_size;

    // ---- CSR build (bucket binning) ----
    hipMemsetAsync(bcnt, 0, (size_t)NB * 4, stream);
    int nbB = (EE + EPB - 1) / EPB;
    bhist_k<<<nbB, 256, 0, stream>>>(e_dst, bcnt);
    bscan_k<<<1, 256, 0, stream>>>(bcnt, bbase, bcur, off);
    bscatter_k<<<nbB, 256, 0, stream>>>(e_src, e_dst, bcur, bedge);
    bcsr_k<<<NB, 512, 0, stream>>>(bedge, bbase, off, csr);

    // ---- weights -> bf16 ----
    cvt6_k<<<(6 * HD * HD) / 256, 256, 0, stream>>>(w_user, w_item, w_l0, w_r0, w_l1, w_r1, wb);

    // ---- input projection (per node type), keys only ----
    proj_mfma_k<<<(NUSR + 127) / 128, 256, 0, stream>>>(x, wb,         b_user, hkey0, 0,    NUSR);
    proj_mfma_k<<<(NITM + 127) / 128, 256, 0, stream>>>(x, wb + 16384, b_item, hkey0, NUSR, NITM);

    // ---- layer 0 ----
    agg_key_k<<<NN / 4, 256, 0, stream>>>((const uint4t*)hkey0, off, csr, (uint4t*)aggb);
    combine_mfma_k<<<(NN + 127) / 128, 256, 0, stream>>>(
        hkey0, aggb, wb + 2 * 16384, b_l0, wb + 3 * 16384, hkey1, nullptr, 1);

    // ---- layer 1 ----
    agg_key_k<<<NN / 4, 256, 0, stream>>>((const uint4t*)hkey1, off, csr, (uint4t*)aggb);
    combine_mfma_k<<<(NN + 127) / 128, 256, 0, stream>>>(
        hkey1, aggb, wb + 4 * 16384, b_l1, wb + 5 * 16384, nullptr, (float*)d_out, 0);
}

// Round 7
// 313.175 us; speedup vs baseline: 1.6945x; 1.2392x over previous
//
#include <hip/hip_runtime.h>

#define NUSR 60000
#define NITM 40000
#define NN   100000
#define EE   2000000
#define HD   128

#define BW   512                 // bucket width in nodes (CSR build)
#define NB   196                 // ceil(NN / BW)
#define EPB  8192                // edges per block in binning kernels

using bf16x8   = __attribute__((ext_vector_type(8))) short;
using f32x4    = __attribute__((ext_vector_type(4))) float;
using ushort4t = __attribute__((ext_vector_type(4))) unsigned short;
using ushort2t = __attribute__((ext_vector_type(2))) unsigned short;
using ushort8t = __attribute__((ext_vector_type(8))) unsigned short;
using uint4t   = __attribute__((ext_vector_type(4))) unsigned int;

__device__ __forceinline__ unsigned short f2bf(float f) {
    unsigned int u = __float_as_uint(f);
    u += 0x7FFFu + ((u >> 16) & 1u);           // round-to-nearest-even
    return (unsigned short)(u >> 16);
}
__device__ __forceinline__ float bf2f(unsigned short s) {
    return __uint_as_float(((unsigned int)s) << 16);
}
// order-preserving bf16 <-> u16 key (unsigned compare order == float order)
__device__ __forceinline__ unsigned short keyof(unsigned short b) {
    return (b & 0x8000u) ? (unsigned short)~b : (unsigned short)(b | 0x8000u);
}
// packed inverse key map on a u32 (2 keys)
__device__ __forceinline__ unsigned unkey32(unsigned k) {
    unsigned negsel = (~k & 0x80008000u) >> 15;
    return k ^ (0x80008000u | (negsel * 0x7FFFu));
}
__device__ __forceinline__ int swz(int row, int col) {
    return row * HD + (col ^ ((row & 7) << 3));
}
__device__ __forceinline__ ushort8t pkmax8(ushort8t a, ushort8t b) {
    return __builtin_elementwise_max(a, b);
}

// ---------------- CSR build via 2-level bucket binning ----------------
__global__ __launch_bounds__(256) void bhist_k(const int* __restrict__ dst,
                                               int* __restrict__ bcnt) {
    __shared__ int h[NB];
    int t = threadIdx.x;
    if (t < NB) h[t] = 0;
    __syncthreads();
    int e0 = blockIdx.x * EPB;
    #pragma unroll 4
    for (int i = t; i < EPB; i += 256) {
        int e = e0 + i;
        if (e < EE) atomicAdd(&h[dst[e] >> 9], 1);
    }
    __syncthreads();
    if (t < NB && h[t]) atomicAdd(&bcnt[t], h[t]);
}

__global__ void bscan_k(const int* __restrict__ bcnt, int* __restrict__ bbase,
                        int* __restrict__ bcur, int* __restrict__ off) {
    __shared__ int s[256];
    int t = threadIdx.x;
    int v = (t < NB) ? bcnt[t] : 0;
    s[t] = v;
    __syncthreads();
    for (int d = 1; d < 256; d <<= 1) {
        int a = (t >= d) ? s[t - d] : 0;
        __syncthreads();
        s[t] += a;
        __syncthreads();
    }
    if (t < NB) { bbase[t] = s[t] - v; bcur[t] = s[t] - v; }
    if (t == NB - 1) { bbase[NB] = s[t]; off[NN] = EE; }
}

__global__ __launch_bounds__(256) void bscatter_k(const int* __restrict__ src,
                                                  const int* __restrict__ dst,
                                                  int* __restrict__ bcur,
                                                  unsigned int* __restrict__ bedge) {
    __shared__ int h[NB], base[NB];
    int t = threadIdx.x;
    if (t < NB) h[t] = 0;
    __syncthreads();
    int e0 = blockIdx.x * EPB;
    #pragma unroll 4
    for (int i = t; i < EPB; i += 256) {
        int e = e0 + i;
        if (e < EE) atomicAdd(&h[dst[e] >> 9], 1);
    }
    __syncthreads();
    if (t < NB) {
        int c = h[t];
        base[t] = c ? atomicAdd(&bcur[t], c) : 0;
        h[t] = 0;
    }
    __syncthreads();
    #pragma unroll 4
    for (int i = t; i < EPB; i += 256) {
        int e = e0 + i;
        if (e < EE) {
            int d = dst[e];
            int b = d >> 9;
            int p = base[b] + atomicAdd(&h[b], 1);
            bedge[p] = ((unsigned)(d - (b << 9)) << 17) | (unsigned)src[e];
        }
    }
}

__global__ __launch_bounds__(512) void bcsr_k(const unsigned int* __restrict__ bedge,
                                              const int* __restrict__ bbase,
                                              int* __restrict__ off,
                                              int* __restrict__ csr) {
    __shared__ int cnt[BW], cur[BW], sc[BW];
    int b = blockIdx.x, t = threadIdx.x;
    int n0 = b * BW;
    int nloc = min(BW, NN - n0);
    cnt[t] = 0;
    __syncthreads();
    int e0 = bbase[b], e1 = bbase[b + 1];
    for (int e = e0 + t; e < e1; e += 512)
        atomicAdd(&cnt[bedge[e] >> 17], 1);
    __syncthreads();
    int v = cnt[t];
    sc[t] = v;
    __syncthreads();
    for (int d = 1; d < BW; d <<= 1) {
        int a = (t >= d) ? sc[t - d] : 0;
        __syncthreads();
        sc[t] += a;
        __syncthreads();
    }
    int excl = sc[t] - v;
    if (t < nloc) { off[n0 + t] = e0 + excl; cur[t] = e0 + excl; }
    __syncthreads();
    for (int e = e0 + t; e < e1; e += 512) {
        unsigned ed = bedge[e];
        int p = atomicAdd(&cur[ed >> 17], 1);
        csr[p] = (int)(ed & 0x1FFFFu);
    }
}

// ---------------- fp32 -> bf16 weight convert (6 mats of 128x128) ------------
__global__ void cvt6_k(const float* __restrict__ a0, const float* __restrict__ a1,
                       const float* __restrict__ a2, const float* __restrict__ a3,
                       const float* __restrict__ a4, const float* __restrict__ a5,
                       unsigned short* __restrict__ out) {
    int i = blockIdx.x * 256 + threadIdx.x;
    const float* s;
    switch (i >> 14) {
        case 0: s = a0; break; case 1: s = a1; break; case 2: s = a2; break;
        case 3: s = a3; break; case 4: s = a4; break; default: s = a5; break;
    }
    out[i] = f2bf(s[i & 16383]);
}

// -------- proj: hkey[row] = key(bf16( x[row] @ w.T + b )), MFMA --------
__global__ __launch_bounds__(256) void proj_mfma_k(
    const float* __restrict__ x, const unsigned short* __restrict__ wb,
    const float* __restrict__ bias, unsigned short* __restrict__ hkey,
    int row_base, int nrows) {
    __shared__ unsigned short lw[HD * HD];       // weights, then reused as key stage
    int tid = threadIdx.x;
    #pragma unroll
    for (int it = 0; it < 16; ++it) {
        int flat = (it * 256 + tid) * 4;
        int row = flat >> 7, col = flat & 127;
        *(ushort4t*)&lw[swz(row, col)] = *(const ushort4t*)(wb + flat);
    }
    __syncthreads();
    int lane = tid & 63, w = tid >> 6;
    int l15 = lane & 15, l4 = lane >> 4;
    int m0 = blockIdx.x * 128 + w * 32;
    f32x4 acc[2][8] = {};
    #pragma unroll
    for (int kb = 0; kb < 4; ++kb) {
        bf16x8 a[2];
        #pragma unroll
        for (int rt = 0; rt < 2; ++rt) {
            int r = m0 + rt * 16 + l15;
            if (r >= nrows) r = nrows - 1;
            const float* ap = x + (size_t)(row_base + r) * HD + kb * 32 + l4 * 8;
            f32x4 v0 = *(const f32x4*)ap;
            f32x4 v1 = *(const f32x4*)(ap + 4);
            bf16x8 f;
            #pragma unroll
            for (int j = 0; j < 4; ++j) { f[j] = (short)f2bf(v0[j]); f[j + 4] = (short)f2bf(v1[j]); }
            a[rt] = f;
        }
        #pragma unroll
        for (int ct = 0; ct < 8; ++ct) {
            bf16x8 b = *(const bf16x8*)&lw[swz(ct * 16 + l15, kb * 32 + l4 * 8)];
            acc[0][ct] = __builtin_amdgcn_mfma_f32_16x16x32_bf16(a[0], b, acc[0][ct], 0, 0, 0);
            acc[1][ct] = __builtin_amdgcn_mfma_f32_16x16x32_bf16(a[1], b, acc[1][ct], 0, 0, 0);
        }
    }
    __syncthreads();                              // weight reads done
    // stage keys into LDS (8-short rotation keeps uint4 contiguity)
    #pragma unroll
    for (int ct = 0; ct < 8; ++ct) {
        int col = ct * 16 + l15;
        float bv = bias[col];
        #pragma unroll
        for (int rt = 0; rt < 2; ++rt)
            #pragma unroll
            for (int j = 0; j < 4; ++j) {
                int lrow = w * 32 + rt * 16 + l4 * 4 + j;
                lw[lrow * HD + ((col + ((lrow & 15) << 3)) & 127)] =
                    keyof(f2bf(acc[rt][ct][j] + bv));
            }
    }
    __syncthreads();
    int row = tid >> 1, cb = (tid & 1) * 64;
    int r = blockIdx.x * 128 + row;
    if (r < nrows) {
        int sof = (row & 15) << 3;
        #pragma unroll
        for (int gg = 0; gg < 8; ++gg) {
            uint4t v = *(const uint4t*)&lw[row * HD + ((cb + gg * 8 + sof) & 127)];
            *(uint4t*)(hkey + (size_t)(row_base + r) * HD + cb + gg * 8) = v;
        }
    }
}

// -------- segment max on u16 keys; coalesced csr + independent gathers -------
__global__ __launch_bounds__(256) void agg_key_k(
    const uint4t* __restrict__ hkey4,            // row = 16 x uint4 (256 B)
    const int* __restrict__ off, const int* __restrict__ csr,
    uint4t* __restrict__ agg4) {
    int node = (blockIdx.x * 256 + threadIdx.x) >> 6;
    int lane = threadIdx.x & 63;
    if (node >= NN) return;
    int s0 = off[node], s1 = off[node + 1];
    int deg = s1 - s0;
    int q = lane >> 4, l16 = lane & 15;
    ushort8t m = {0, 0, 0, 0, 0, 0, 0, 0};       // 0 < key(any finite bf16)
    // fast path: one coalesced csr read covers first 64 edges; 16 independent gathers
    int cval = (lane < deg) ? csr[s0 + lane] : 0;
    int nslots = deg < 64 ? deg : 64;
    #pragma unroll
    for (int u = 0; u < 16; ++u) {
        int idx = u * 4 + q;
        int r = __shfl(cval, idx, 64);           // all lanes participate
        if (idx < nslots) {
            uint4t v = hkey4[(size_t)r * 16 + l16];
            m = pkmax8(m, *(ushort8t*)&v);
        }
    }
    // rare tail: deg > 64
    for (int base = s0 + 64; base < s1; base += 32) {
        #pragma unroll
        for (int u = 0; u < 8; ++u) {
            int jj = base + u * 4 + q;
            if (jj < s1) {
                int r = csr[jj];
                uint4t v = hkey4[(size_t)r * 16 + l16];
                m = pkmax8(m, *(ushort8t*)&v);
            }
        }
    }
    // merge the 4 quarters (xor-16 then xor-32), per u32 component
    uint4t mu = *(uint4t*)&m;
    #pragma unroll
    for (int c = 0; c < 4; ++c) {
        unsigned a = mu[c];
        unsigned b = (unsigned)__shfl_xor((int)a, 16, 64);
        ushort2t pa = *(ushort2t*)&a, pb = *(ushort2t*)&b;
        pa = __builtin_elementwise_max(pa, pb);
        a = *(unsigned*)&pa;
        b = (unsigned)__shfl_xor((int)a, 32, 64);
        pb = *(ushort2t*)&b;
        pa = __builtin_elementwise_max(pa, pb);
        mu[c] = *(unsigned*)&pa;
    }
    if (q == 0) {
        uint4t outv = {0, 0, 0, 0};
        if (deg > 0) {
            #pragma unroll
            for (int c = 0; c < 4; ++c) outv[c] = unkey32(mu[c]);
        }
        agg4[(size_t)node * 16 + l16] = outv;
    }
}

// ----- combine: out = h + bl + agg@wl.T + h@wr.T (relu?), coalesced epilogue -
__global__ __launch_bounds__(256) void combine_mfma_k(
    const unsigned short* __restrict__ hkey, const unsigned short* __restrict__ aggb,
    const unsigned short* __restrict__ wlb, const float* __restrict__ bl,
    const unsigned short* __restrict__ wrb,
    unsigned short* __restrict__ hkey_out, float* __restrict__ fout, int relu) {
    __shared__ unsigned short lw[2][HD * HD];    // 64 KB weights; reused as fp32 C
    int tid = threadIdx.x;
    #pragma unroll
    for (int it = 0; it < 16; ++it) {
        int flat = (it * 256 + tid) * 4;
        int row = flat >> 7, col = flat & 127;
        *(ushort4t*)&lw[0][swz(row, col)] = *(const ushort4t*)(wlb + flat);
        *(ushort4t*)&lw[1][swz(row, col)] = *(const ushort4t*)(wrb + flat);
    }
    __syncthreads();
    int lane = tid & 63, w = tid >> 6;
    int l15 = lane & 15, l4 = lane >> 4;
    int m0 = blockIdx.x * 128 + w * 32;
    const uint4t* hk4 = (const uint4t*)hkey;
    f32x4 acc[2][8] = {};
    #pragma unroll
    for (int kb = 0; kb < 4; ++kb) {
        bf16x8 a1[2], a2[2];
        #pragma unroll
        for (int rt = 0; rt < 2; ++rt) {
            int r = m0 + rt * 16 + l15;
            if (r >= NN) r = NN - 1;
            size_t o = (size_t)r * HD + kb * 32 + l4 * 8;
            a1[rt] = *(const bf16x8*)(aggb + o);
            uint4t aw = hk4[(size_t)r * 16 + kb * 4 + l4];
            bf16x8 f;
            #pragma unroll
            for (int u = 0; u < 4; ++u) {
                unsigned d = unkey32(aw[u]);
                f[2 * u]     = (short)(d & 0xFFFFu);
                f[2 * u + 1] = (short)(d >> 16);
            }
            a2[rt] = f;
        }
        #pragma unroll
        for (int ct = 0; ct < 8; ++ct) {
            bf16x8 b1 = *(const bf16x8*)&lw[0][swz(ct * 16 + l15, kb * 32 + l4 * 8)];
            bf16x8 b2 = *(const bf16x8*)&lw[1][swz(ct * 16 + l15, kb * 32 + l4 * 8)];
            acc[0][ct] = __builtin_amdgcn_mfma_f32_16x16x32_bf16(a1[0], b1, acc[0][ct], 0, 0, 0);
            acc[0][ct] = __builtin_amdgcn_mfma_f32_16x16x32_bf16(a2[0], b2, acc[0][ct], 0, 0, 0);
            acc[1][ct] = __builtin_amdgcn_mfma_f32_16x16x32_bf16(a1[1], b1, acc[1][ct], 0, 0, 0);
            acc[1][ct] = __builtin_amdgcn_mfma_f32_16x16x32_bf16(a2[1], b2, acc[1][ct], 0, 0, 0);
        }
    }
    __syncthreads();                              // weight reads done
    // stage fp32 C into LDS, (col+row)&127 rotation -> conflict-light
    float* cs = (float*)lw;
    #pragma unroll
    for (int ct = 0; ct < 8; ++ct)
        #pragma unroll
        for (int rt = 0; rt < 2; ++rt)
            #pragma unroll
            for (int j = 0; j < 4; ++j) {
                int lrow = w * 32 + rt * 16 + l4 * 4 + j;
                int col = ct * 16 + l15;
                cs[lrow * HD + ((col + lrow) & 127)] = acc[rt][ct][j];
            }
    __syncthreads();
    // epilogue: 2 threads per row, 64 cols each, fully coalesced
    int row = tid >> 1, cb = (tid & 1) * 64;
    int r = blockIdx.x * 128 + row;
    if (r < NN) {
        const uint4t* resrow = (const uint4t*)(hkey + (size_t)r * HD + cb);
        uint4t res[8];
        #pragma unroll
        for (int g = 0; g < 8; ++g) res[g] = resrow[g];
        if (fout) {
            #pragma unroll
            for (int gg = 0; gg < 8; ++gg) {
                f32x4 va, vb;
                #pragma unroll
                for (int u = 0; u < 4; ++u) {
                    int c0 = cb + gg * 8 + u * 2;
                    unsigned d = unkey32(res[gg][u]);
                    float v0 = cs[row * HD + ((c0 + row) & 127)] + bl[c0]
                             + bf2f((unsigned short)(d & 0xFFFFu));
                    float v1 = cs[row * HD + ((c0 + 1 + row) & 127)] + bl[c0 + 1]
                             + bf2f((unsigned short)(d >> 16));
                    if (relu) { v0 = fmaxf(v0, 0.0f); v1 = fmaxf(v1, 0.0f); }
                    if (u < 2) { va[u * 2] = v0; va[u * 2 + 1] = v1; }
                    else       { vb[(u - 2) * 2] = v0; vb[(u - 2) * 2 + 1] = v1; }
                }
                *(f32x4*)(fout + (size_t)r * HD + cb + gg * 8) = va;
                *(f32x4*)(fout + (size_t)r * HD + cb + gg * 8 + 4) = vb;
            }
        } else {
            #pragma unroll
            for (int gg = 0; gg < 8; ++gg) {
                uint4t ov;
                #pragma unroll
                for (int u = 0; u < 4; ++u) {
                    int c0 = cb + gg * 8 + u * 2;
                    unsigned d = unkey32(res[gg][u]);
                    float v0 = cs[row * HD + ((c0 + row) & 127)] + bl[c0]
                             + bf2f((unsigned short)(d & 0xFFFFu));
                    float v1 = cs[row * HD + ((c0 + 1 + row) & 127)] + bl[c0 + 1]
                             + bf2f((unsigned short)(d >> 16));
                    if (relu) { v0 = fmaxf(v0, 0.0f); v1 = fmaxf(v1, 0.0f); }
                    ov[u] = (unsigned)keyof(f2bf(v0)) | ((unsigned)keyof(f2bf(v1)) << 16);
                }
                *(uint4t*)(hkey_out + (size_t)r * HD + cb + gg * 8) = ov;
            }
        }
    }
}

extern "C" void kernel_launch(void* const* d_in, const int* in_sizes, int n_in,
                              void* d_out, int out_size, void* d_ws, size_t ws_size,
                              hipStream_t stream) {
    const float* x      = (const float*)d_in[0];
    const int*   ei     = (const int*)d_in[1];
    const float* w_user = (const float*)d_in[3];
    const float* b_user = (const float*)d_in[4];
    const float* w_item = (const float*)d_in[5];
    const float* b_item = (const float*)d_in[6];
    const float* w_l0   = (const float*)d_in[7];
    const float* b_l0   = (const float*)d_in[8];
    const float* w_r0   = (const float*)d_in[9];
    const float* w_l1   = (const float*)d_in[10];
    const float* b_l1   = (const float*)d_in[11];
    const float* w_r1   = (const float*)d_in[12];

    const int* e_src = ei;
    const int* e_dst = ei + EE;

    char* ws = (char*)d_ws;
    size_t cur_off = 0;
    auto carve = [&](size_t bytes) {
        void* p = ws + cur_off;
        cur_off = (cur_off + bytes + 255) & ~(size_t)255;
        return p;
    };
    unsigned short* hkey0 = (unsigned short*)carve((size_t)NN * HD * 2);  // 25.6 MB
    unsigned short* hkey1 = (unsigned short*)carve((size_t)NN * HD * 2);
    unsigned short* aggb  = (unsigned short*)carve((size_t)NN * HD * 2);
    unsigned short* wb    = (unsigned short*)carve((size_t)6 * HD * HD * 2);
    int*      off   = (int*)carve((size_t)(NN + 1) * 4);
    int*      csr   = (int*)carve((size_t)EE * 4);
    unsigned* bedge = (unsigned*)carve((size_t)EE * 4);
    int*      bcnt  = (int*)carve((NB + 1) * 4);
    int*      bbase = (int*)carve((NB + 1) * 4);
    int*      bcur  = (int*)carve((NB + 1) * 4);
    (void)ws_size;

    // ---- CSR build (bucket binning) ----
    hipMemsetAsync(bcnt, 0, (size_t)NB * 4, stream);
    int nbB = (EE + EPB - 1) / EPB;
    bhist_k<<<nbB, 256, 0, stream>>>(e_dst, bcnt);
    bscan_k<<<1, 256, 0, stream>>>(bcnt, bbase, bcur, off);
    bscatter_k<<<nbB, 256, 0, stream>>>(e_src, e_dst, bcur, bedge);
    bcsr_k<<<NB, 512, 0, stream>>>(bedge, bbase, off, csr);

    // ---- weights -> bf16 ----
    cvt6_k<<<(6 * HD * HD) / 256, 256, 0, stream>>>(w_user, w_item, w_l0, w_r0, w_l1, w_r1, wb);

    // ---- input projection (per node type), keys only ----
    proj_mfma_k<<<(NUSR + 127) / 128, 256, 0, stream>>>(x, wb,         b_user, hkey0, 0,    NUSR);
    proj_mfma_k<<<(NITM + 127) / 128, 256, 0, stream>>>(x, wb + 16384, b_item, hkey0, NUSR, NITM);

    // ---- layer 0 ----
    agg_key_k<<<NN / 4, 256, 0, stream>>>((const uint4t*)hkey0, off, csr, (uint4t*)aggb);
    combine_mfma_k<<<(NN + 127) / 128, 256, 0, stream>>>(
        hkey0, aggb, wb + 2 * 16384, b_l0, wb + 3 * 16384, hkey1, nullptr, 1);

    // ---- layer 1 ----
    agg_key_k<<<NN / 4, 256, 0, stream>>>((const uint4t*)hkey1, off, csr, (uint4t*)aggb);
    combine_mfma_k<<<(NN + 127) / 128, 256, 0, stream>>>(
        hkey1, aggb, wb + 4 * 16384, b_l1, wb + 5 * 16384, nullptr, (float*)d_out, 0);
}